// Round 3
// baseline (2481.352 us; speedup 1.0000x reference)
//
#include <hip/hip_runtime.h>
#include <cstdint>
#include <cstddef>

#define T_STEPS 1024
#define NB 64
#define DIN 256
#define DH 256
#define DW 512            // DIN + DH (row width of each W)
#define G4 1024           // 4*DH gate rows
#define KR 184            // k-values of recurrent weights held in registers
#define KRH (KR/2)        // 92 h2 registers
#define NTAIL ((DH-KR)/8) // 9 LDS chunks of 8 f16 per row

typedef _Float16 h2 __attribute__((ext_vector_type(2)));
typedef _Float16 h4 __attribute__((ext_vector_type(4)));
typedef _Float16 h8 __attribute__((ext_vector_type(8)));
typedef float f4 __attribute__((ext_vector_type(4)));

// Build h2 = (v[2m], v[2m+1]). Dynamic subscripts constant-fold after unroll.
static __device__ __forceinline__ h2 sl2(h8 v, int m) {
  h2 r; r[0] = v[2 * m]; r[1] = v[2 * m + 1]; return r;
}
static __device__ __forceinline__ h2 sl2_4(h4 v, int m) {
  h2 r; r[0] = v[2 * m]; r[1] = v[2 * m + 1]; return r;
}

static __device__ __forceinline__ float fdot2(h2 a, h2 b, float c) {
#if __has_builtin(__builtin_amdgcn_fdot2)
  return __builtin_amdgcn_fdot2(a, b, c, false);
#else
  return c + (float)a[0]*(float)b[0] + (float)a[1]*(float)b[1];
#endif
}

static __device__ __forceinline__ float rcp_(float x) {
#if __has_builtin(__builtin_amdgcn_rcpf)
  return __builtin_amdgcn_rcpf(x);
#else
  return 1.0f / x;
#endif
}

static __device__ __forceinline__ float sigmoid_(float x) {
  x = fminf(fmaxf(x, -30.f), 30.f);
  return rcp_(1.f + __expf(-x));
}
static __device__ __forceinline__ float tanh_(float x) {
  x = fminf(fmaxf(x, -15.f), 15.f);
  float e = __expf(2.f * x);
  return 1.f - 2.f * rcp_(e + 1.f);
}

// ---------------------------------------------------------------------------
// Weight pre-conversion.
//  wxhT[kp][gr]  = (W[gr][2kp], W[gr][2kp+1])         x-part, k-pair-major (for kxgemm)
//  wrowh[gr][kp] = (W[gr][256+2kp], W[gr][256+2kp+1]) h-part, row-major   (for klstm)
// grid: 512 blocks (kp = bid>>2, gate = bid&3), 256 threads (j)
// ---------------------------------------------------------------------------
__global__ void kconv_w(const float* __restrict__ Wf, const float* __restrict__ Wi,
                        const float* __restrict__ Wg, const float* __restrict__ Wo,
                        h2* __restrict__ wxhT, h2* __restrict__ wrowh) {
  int kp = blockIdx.x >> 2;
  int gate = blockIdx.x & 3;
  int j = threadIdx.x;
  const float* W = gate == 0 ? Wf : gate == 1 ? Wi : gate == 2 ? Wg : Wo;
  const float* row = W + (size_t)j * DW;
  h2 v; v[0] = (_Float16)row[2*kp]; v[1] = (_Float16)row[2*kp + 1];
  wxhT[(size_t)kp * G4 + gate * DH + j] = v;
  h2 u; u[0] = (_Float16)row[DIN + 2*kp]; u[1] = (_Float16)row[DIN + 2*kp + 1];
  wrowh[((size_t)gate * DH + j) * 128 + kp] = u;
}

// ---------------------------------------------------------------------------
// Phase 1: Xg[t_local][b][gr] = x[t][b][:] . Wx[gr][:] + bias[gr]   (f16 out)
// (unchanged from round 2 — MFMA rewrite deferred)
// ---------------------------------------------------------------------------
__launch_bounds__(256, 2)
__global__ void kxgemm(const float* __restrict__ x,
                       const h2* __restrict__ wxhT,
                       const float* __restrict__ bf, const float* __restrict__ bi,
                       const float* __restrict__ bg, const float* __restrict__ bo,
                       _Float16* __restrict__ Xg,
                       int t0) {
  __shared__ h2 xs[64 * 64];    // [row 64][kp 64]  16KB (per K-stage)
  __shared__ h2 wsT[64 * 256];  // [kp 64][gate 256] 64KB (per K-stage)

  int tid = threadIdx.x;
  int tg = tid & 31, tr = tid >> 5;
  int tb = blockIdx.x >> 2, gb = blockIdx.x & 3;
  size_t xrow0 = ((size_t)(t0 + tb)) * NB;

  float acc[8][8];
#pragma unroll
  for (int r = 0; r < 8; ++r)
#pragma unroll
    for (int g = 0; g < 8; ++g) acc[r][g] = 0.f;

  for (int ks = 0; ks < 2; ++ks) {
#pragma unroll
    for (int i = 0; i < 8; ++i) {
      int idx = tid + 256 * i;
      int r = idx >> 5, k4 = idx & 31;
      f4 v = *(const f4*)(x + (xrow0 + r) * DIN + ks * 128 + k4 * 4);
      h4 p;
      p[0] = (_Float16)v[0]; p[1] = (_Float16)v[1];
      p[2] = (_Float16)v[2]; p[3] = (_Float16)v[3];
      *(h4*)(void*)(xs + (size_t)r * 64 + 2 * k4) = p;
    }
#pragma unroll
    for (int i = 0; i < 16; ++i) {
      int idx = tid + 256 * i;
      int kp = idx >> 6, g4 = idx & 63;
      f4 v = *(const f4*)(const void*)(wxhT + (size_t)(ks * 64 + kp) * G4 + gb * DH + g4 * 4);
      *(f4*)(void*)(wsT + (size_t)kp * 256 + g4 * 4) = v;
    }
    __syncthreads();

#pragma unroll 2
    for (int kp2 = 0; kp2 < 32; ++kp2) {
      h4 xv[8];
#pragma unroll
      for (int r = 0; r < 8; ++r)
        xv[r] = *(const h4*)(const void*)(xs + (size_t)(tr * 8 + r) * 64 + 2 * kp2);
      h8 w0a = *(const h8*)(const void*)(wsT + (size_t)(2 * kp2) * 256 + tg * 8);
      h8 w0b = *(const h8*)(const void*)(wsT + (size_t)(2 * kp2) * 256 + tg * 8 + 4);
      h8 w1a = *(const h8*)(const void*)(wsT + (size_t)(2 * kp2 + 1) * 256 + tg * 8);
      h8 w1b = *(const h8*)(const void*)(wsT + (size_t)(2 * kp2 + 1) * 256 + tg * 8 + 4);
#pragma unroll
      for (int r = 0; r < 8; ++r) {
        h2 x0 = sl2_4(xv[r], 0);
        h2 x1 = sl2_4(xv[r], 1);
#pragma unroll
        for (int g = 0; g < 4; ++g) {
          acc[r][g] = fdot2(x0, sl2(w0a, g), acc[r][g]);
          acc[r][g] = fdot2(x1, sl2(w1a, g), acc[r][g]);
        }
#pragma unroll
        for (int g = 0; g < 4; ++g) {
          acc[r][4 + g] = fdot2(x0, sl2(w0b, g), acc[r][4 + g]);
          acc[r][4 + g] = fdot2(x1, sl2(w1b, g), acc[r][4 + g]);
        }
      }
    }
    __syncthreads();
  }

  const float* bias = gb == 0 ? bf : gb == 1 ? bi : gb == 2 ? bg : bo;
  float bv[8];
#pragma unroll
  for (int g = 0; g < 8; ++g) bv[g] = bias[tg * 8 + g];
#pragma unroll
  for (int r = 0; r < 8; ++r) {
    h8 o;
#pragma unroll
    for (int g = 0; g < 8; ++g) o[g] = (_Float16)(acc[r][g] + bv[g]);
    *(h8*)(void*)(Xg + ((size_t)tb * NB + tr * 8 + r) * G4 + gb * DH + tg * 8) = o;
  }
}

// ---------------------------------------------------------------------------
// Phase 2: sequential LSTM. One workgroup per batch element (sync-free).
// 1024 threads; QUAD mapping: gate = tid&3, j = tid>>2 — the 4 gate rows of
// one hidden unit live in adjacent lanes, so activation exchange is 4 shfl
// (no acts LDS, no second barrier). hbuf double-buffered -> 1 barrier/step.
// Weights: K [0,184) f16 in registers (92 VGPRs), K [184,256) in LDS (144KB).
// ---------------------------------------------------------------------------
__global__ __launch_bounds__(1024) __attribute__((amdgpu_waves_per_eu(4, 4)))
void klstm(const h2* __restrict__ wrowh,
           const _Float16* __restrict__ Xg,
           const float* __restrict__ hsrc, const float* __restrict__ csrc,
           float* __restrict__ out,
           float* __restrict__ hN, float* __restrict__ cN,
           int t0, int Tc) {
  __shared__ h8 wlds[NTAIL][1024];  // 9*16KB = 144KB, [chunk][tid] conflict-free
  __shared__ h2 hbuf[2][DH / 2];    // double-buffered current h (f16)

  int tid = threadIdx.x;
  int b = blockIdx.x;
  int g = tid & 3;
  int j = tid >> 2;
  int row = g * DH + j;
  int lb = tid & 60;  // lane base of this quad within the wave

  const h2* wr = wrowh + (size_t)row * 128;

  // recurrent weights K[0,184) -> registers (direct h2 loads, no converts)
  h2 wa[KRH];
#pragma unroll
  for (int q = 0; q < KRH / 4; ++q) {
    h8 v = *(const h8*)(const void*)(wr + 4 * q);
    wa[4 * q + 0] = sl2(v, 0);
    wa[4 * q + 1] = sl2(v, 1);
    wa[4 * q + 2] = sl2(v, 2);
    wa[4 * q + 3] = sl2(v, 3);
  }
  // K[184,256) tail -> LDS
#pragma unroll
  for (int cc = 0; cc < NTAIL; ++cc)
    wlds[cc][tid] = *(const h8*)(const void*)(wr + KRH + 4 * cc);

  float creg = csrc[(size_t)b * DH + j];  // replicated across the quad
  if (tid < 128) {
    h2 hv;
    hv[0] = (_Float16)hsrc[(size_t)b * DH + 2 * tid];
    hv[1] = (_Float16)hsrc[(size_t)b * DH + 2 * tid + 1];
    hbuf[0][tid] = hv;
  }
  __syncthreads();

  const size_t xstep = (size_t)NB * G4;
  const _Float16* xp = Xg + (size_t)b * G4 + row;
  float xcur = (float)xp[0];
  float hlast = 0.f;

  for (int t = 0; t < Tc; ++t) {
    float xnext = (t + 1 < Tc) ? (float)xp[(size_t)(t + 1) * xstep] : 0.f;
    const h2* hb = hbuf[t & 1];

    float acc = xcur;  // x-part + bias (precomputed)
#pragma unroll
    for (int q = 0; q < KRH / 4; ++q) {
      h8 hv = *(const h8*)(const void*)(hb + 4 * q);  // 16B broadcast
      acc = fdot2(wa[4 * q + 0], sl2(hv, 0), acc);
      acc = fdot2(wa[4 * q + 1], sl2(hv, 1), acc);
      acc = fdot2(wa[4 * q + 2], sl2(hv, 2), acc);
      acc = fdot2(wa[4 * q + 3], sl2(hv, 3), acc);
    }
#pragma unroll
    for (int cc = 0; cc < NTAIL; ++cc) {
      h8 hv = *(const h8*)(const void*)(hb + KRH + 4 * cc);  // broadcast
      h8 wv = wlds[cc][tid];
      acc = fdot2(sl2(wv, 0), sl2(hv, 0), acc);
      acc = fdot2(sl2(wv, 1), sl2(hv, 1), acc);
      acc = fdot2(sl2(wv, 2), sl2(hv, 2), acc);
      acc = fdot2(sl2(wv, 3), sl2(hv, 3), acc);
    }

    // branchless activation: gate 2 -> tanh = 2*sigmoid(2x)-1, else sigmoid
    float y = (g == 2) ? 2.f * acc : acc;
    float s = sigmoid_(y);
    float act = (g == 2) ? (2.f * s - 1.f) : s;

    // quad exchange: f,i,g,o
    float f_ = __shfl(act, lb | 0);
    float i_ = __shfl(act, lb | 1);
    float g_ = __shfl(act, lb | 2);
    float o_ = __shfl(act, lb | 3);

    creg = f_ * creg + i_ * g_;
    float hn = o_ * tanh_(creg);
    hlast = hn;
    if (g == 0) {
      out[((size_t)(t0 + t) * NB + b) * DH + j] = hn;
      ((_Float16*)hbuf[(t + 1) & 1])[j] = (_Float16)hn;
    }
    __syncthreads();
    xcur = xnext;
  }

  if (g == 0) {
    hN[(size_t)b * DH + j] = hlast;
    cN[(size_t)b * DH + j] = creg;
  }
}

// ---------------------------------------------------------------------------
extern "C" void kernel_launch(void* const* d_in, const int* in_sizes, int n_in,
                              void* d_out, int out_size, void* d_ws, size_t ws_size,
                              hipStream_t stream) {
  if (n_in < 11) return;
  const float* x  = (const float*)d_in[0];
  const float* h0 = (const float*)d_in[1];
  const float* c0 = (const float*)d_in[2];
  const float* Wf = (const float*)d_in[3];
  const float* bf = (const float*)d_in[4];
  const float* Wi = (const float*)d_in[5];
  const float* bi = (const float*)d_in[6];
  const float* Wg = (const float*)d_in[7];
  const float* bg = (const float*)d_in[8];
  const float* Wo = (const float*)d_in[9];
  const float* bo = (const float*)d_in[10];

  float* out = (float*)d_out;
  float* hN = out + (size_t)T_STEPS * NB * DH;
  float* cN = hN + (size_t)NB * DH;

  // ws layout: [Xg ring: Tc*128KB][wxhT 512KB][wrowh 512KB]
  const size_t wxhBytes = (size_t)128 * G4 * sizeof(h2);   // 512KB
  const size_t wrowBytes = (size_t)G4 * 128 * sizeof(h2);  // 512KB
  const size_t fixedBytes = wxhBytes + wrowBytes;
  size_t avail = (ws_size > fixedBytes + 256) ? ws_size - fixedBytes - 256 : 0;
  const size_t perT = (size_t)NB * G4 * 2;  // 128KB per time step
  int Tc = (int)(avail / perT);
  if (Tc > T_STEPS) Tc = T_STEPS;
  if (Tc < 1) Tc = 1;

  _Float16* Xg = (_Float16*)d_ws;
  size_t xgBytes = ((size_t)Tc * perT + 255) / 256 * 256;
  h2* wxhT = (h2*)((char*)d_ws + xgBytes);
  h2* wrowh = (h2*)((char*)d_ws + xgBytes + wxhBytes);

  kconv_w<<<dim3(512), dim3(256), 0, stream>>>(Wf, Wi, Wg, Wo, wxhT, wrowh);

  for (int t0 = 0; t0 < T_STEPS; t0 += Tc) {
    int tc = (T_STEPS - t0 < Tc) ? (T_STEPS - t0) : Tc;
    kxgemm<<<dim3(tc * 4), dim3(256), 0, stream>>>(x, wxhT, bf, bi, bg, bo, Xg, t0);
    const float* hs = (t0 == 0) ? h0 : hN;
    const float* cs = (t0 == 0) ? c0 : cN;
    klstm<<<dim3(NB), dim3(1024), 0, stream>>>(wrowh, Xg, hs, cs,
                                               out, hN, cN, t0, tc);
  }
}

// Round 4
// 2009.816 us; speedup vs baseline: 1.2346x; 1.2346x over previous
//
#include <hip/hip_runtime.h>
#include <cstdint>
#include <cstddef>

#define T_STEPS 1024
#define NB 64
#define DIN 256
#define DH 256
#define DW 512            // DIN + DH (row width of each W)
#define G4 1024           // 4*DH gate rows

typedef _Float16 h2 __attribute__((ext_vector_type(2)));
typedef _Float16 h4 __attribute__((ext_vector_type(4)));
typedef _Float16 h8 __attribute__((ext_vector_type(8)));
typedef float f4 __attribute__((ext_vector_type(4)));

// Build h2 = (v[2m], v[2m+1]). Dynamic subscripts constant-fold after unroll.
static __device__ __forceinline__ h2 sl2(h8 v, int m) {
  h2 r; r[0] = v[2 * m]; r[1] = v[2 * m + 1]; return r;
}
static __device__ __forceinline__ h2 sl2_4(h4 v, int m) {
  h2 r; r[0] = v[2 * m]; r[1] = v[2 * m + 1]; return r;
}

static __device__ __forceinline__ float fdot2(h2 a, h2 b, float c) {
#if __has_builtin(__builtin_amdgcn_fdot2)
  return __builtin_amdgcn_fdot2(a, b, c, false);
#else
  return c + (float)a[0]*(float)b[0] + (float)a[1]*(float)b[1];
#endif
}

static __device__ __forceinline__ float rcp_(float x) {
#if __has_builtin(__builtin_amdgcn_rcpf)
  return __builtin_amdgcn_rcpf(x);
#else
  return 1.0f / x;
#endif
}

static __device__ __forceinline__ float sigmoid_(float x) {
  x = fminf(fmaxf(x, -30.f), 30.f);
  return rcp_(1.f + __expf(-x));
}
static __device__ __forceinline__ float tanh_(float x) {
  x = fminf(fmaxf(x, -15.f), 15.f);
  float e = __expf(2.f * x);
  return 1.f - 2.f * rcp_(e + 1.f);
}

// Pairwise lane swap (0<->1, 2<->3, ...) via DPP quad_perm [1,0,3,2] — pure
// VALU, no LDS-pipe traffic (replaces __shfl_xor which lowers to ds_swizzle).
static __device__ __forceinline__ float dpp_swap1(float x) {
#if __has_builtin(__builtin_amdgcn_update_dpp)
  int r = __builtin_amdgcn_update_dpp(0, __builtin_bit_cast(int, x),
                                      0xB1, 0xF, 0xF, true);
  return __builtin_bit_cast(float, r);
#else
  return __shfl_xor(x, 1);
#endif
}

// ---------------------------------------------------------------------------
// Weight pre-conversion (unchanged).
//  wxhT[kp][gr]  = x-part, k-pair-major (for kxgemm)
//  wrowh[gr][kp] = h-part, row-major    (for klstm)
// ---------------------------------------------------------------------------
__global__ void kconv_w(const float* __restrict__ Wf, const float* __restrict__ Wi,
                        const float* __restrict__ Wg, const float* __restrict__ Wo,
                        h2* __restrict__ wxhT, h2* __restrict__ wrowh) {
  int kp = blockIdx.x >> 2;
  int gate = blockIdx.x & 3;
  int j = threadIdx.x;
  const float* W = gate == 0 ? Wf : gate == 1 ? Wi : gate == 2 ? Wg : Wo;
  const float* row = W + (size_t)j * DW;
  h2 v; v[0] = (_Float16)row[2*kp]; v[1] = (_Float16)row[2*kp + 1];
  wxhT[(size_t)kp * G4 + gate * DH + j] = v;
  h2 u; u[0] = (_Float16)row[DIN + 2*kp]; u[1] = (_Float16)row[DIN + 2*kp + 1];
  wrowh[((size_t)gate * DH + j) * 128 + kp] = u;
}

// ---------------------------------------------------------------------------
// Phase 1: Xg[t][b][gr] = x[t][b][:] . Wx[gr][:] + bias[gr]   (f16 out)
// (unchanged from round 2)
// ---------------------------------------------------------------------------
__launch_bounds__(256, 2)
__global__ void kxgemm(const float* __restrict__ x,
                       const h2* __restrict__ wxhT,
                       const float* __restrict__ bf, const float* __restrict__ bi,
                       const float* __restrict__ bg, const float* __restrict__ bo,
                       _Float16* __restrict__ Xg,
                       int t0) {
  __shared__ h2 xs[64 * 64];
  __shared__ h2 wsT[64 * 256];

  int tid = threadIdx.x;
  int tg = tid & 31, tr = tid >> 5;
  int tb = blockIdx.x >> 2, gb = blockIdx.x & 3;
  size_t xrow0 = ((size_t)(t0 + tb)) * NB;

  float acc[8][8];
#pragma unroll
  for (int r = 0; r < 8; ++r)
#pragma unroll
    for (int g = 0; g < 8; ++g) acc[r][g] = 0.f;

  for (int ks = 0; ks < 2; ++ks) {
#pragma unroll
    for (int i = 0; i < 8; ++i) {
      int idx = tid + 256 * i;
      int r = idx >> 5, k4 = idx & 31;
      f4 v = *(const f4*)(x + (xrow0 + r) * DIN + ks * 128 + k4 * 4);
      h4 p;
      p[0] = (_Float16)v[0]; p[1] = (_Float16)v[1];
      p[2] = (_Float16)v[2]; p[3] = (_Float16)v[3];
      *(h4*)(void*)(xs + (size_t)r * 64 + 2 * k4) = p;
    }
#pragma unroll
    for (int i = 0; i < 16; ++i) {
      int idx = tid + 256 * i;
      int kp = idx >> 6, g4 = idx & 63;
      f4 v = *(const f4*)(const void*)(wxhT + (size_t)(ks * 64 + kp) * G4 + gb * DH + g4 * 4);
      *(f4*)(void*)(wsT + (size_t)kp * 256 + g4 * 4) = v;
    }
    __syncthreads();

#pragma unroll 2
    for (int kp2 = 0; kp2 < 32; ++kp2) {
      h4 xv[8];
#pragma unroll
      for (int r = 0; r < 8; ++r)
        xv[r] = *(const h4*)(const void*)(xs + (size_t)(tr * 8 + r) * 64 + 2 * kp2);
      h8 w0a = *(const h8*)(const void*)(wsT + (size_t)(2 * kp2) * 256 + tg * 8);
      h8 w0b = *(const h8*)(const void*)(wsT + (size_t)(2 * kp2) * 256 + tg * 8 + 4);
      h8 w1a = *(const h8*)(const void*)(wsT + (size_t)(2 * kp2 + 1) * 256 + tg * 8);
      h8 w1b = *(const h8*)(const void*)(wsT + (size_t)(2 * kp2 + 1) * 256 + tg * 8 + 4);
#pragma unroll
      for (int r = 0; r < 8; ++r) {
        h2 x0 = sl2_4(xv[r], 0);
        h2 x1 = sl2_4(xv[r], 1);
#pragma unroll
        for (int g = 0; g < 4; ++g) {
          acc[r][g] = fdot2(x0, sl2(w0a, g), acc[r][g]);
          acc[r][g] = fdot2(x1, sl2(w1a, g), acc[r][g]);
        }
#pragma unroll
        for (int g = 0; g < 4; ++g) {
          acc[r][4 + g] = fdot2(x0, sl2(w0b, g), acc[r][4 + g]);
          acc[r][4 + g] = fdot2(x1, sl2(w1b, g), acc[r][4 + g]);
        }
      }
    }
    __syncthreads();
  }

  const float* bias = gb == 0 ? bf : gb == 1 ? bi : gb == 2 ? bg : bo;
  float bv[8];
#pragma unroll
  for (int g = 0; g < 8; ++g) bv[g] = bias[tg * 8 + g];
#pragma unroll
  for (int r = 0; r < 8; ++r) {
    h8 o;
#pragma unroll
    for (int g = 0; g < 8; ++g) o[g] = (_Float16)(acc[r][g] + bv[g]);
    *(h8*)(void*)(Xg + ((size_t)tb * NB + tr * 8 + r) * G4 + gb * DH + tg * 8) = o;
  }
}

// ---------------------------------------------------------------------------
// Phase 2: sequential LSTM. One workgroup per batch (sync-free), 512 threads.
// Thread (j = tid>>1, p = tid&1) holds ALL FOUR gate rows of unit j over its
// K-half (k in [p*128,(p+1)*128)): 13 h8 chunks/row in NAMED registers
// (52 h8 = 208 VGPRs; no arrays -> no AGPR/scratch demotion), 3 h8/row in LDS.
// Partial gate sums combined across the lane pair via DPP quad-perm swap
// (VALU, no LDS). Both lanes then compute activations + c redundantly.
// h broadcast: 16 b128 reads/thread/step (2-addr per wave = conflict-free).
// ---------------------------------------------------------------------------
#define CH13(M) M(0) M(1) M(2) M(3) M(4) M(5) M(6) M(7) M(8) M(9) M(10) M(11) M(12)

__global__ __launch_bounds__(512) __attribute__((amdgpu_waves_per_eu(2, 2)))
void klstm(const h2* __restrict__ wrowh,
           const _Float16* __restrict__ Xg,
           const float* __restrict__ hsrc, const float* __restrict__ csrc,
           float* __restrict__ out,
           float* __restrict__ hN, float* __restrict__ cN,
           int t0, int Tc) {
  __shared__ h8 wtail[12][512];   // 96KB: rows F(0..2) I(3..5) G(6..8) O(9..11)
  __shared__ h2 hbuf[2][DH / 2];  // double-buffered h (f16), 1KB

  int tid = threadIdx.x;
  int b = blockIdx.x;
  int p = tid & 1;
  int j = tid >> 1;
  int P16 = p * 16;      // this thread's first h8-chunk of K
  int hoff = p * 64;     // h2 offset of this thread's K-half in hbuf

  const h2* rowF = wrowh + ((size_t)0 * DH + j) * 128;
  const h2* rowI = wrowh + ((size_t)1 * DH + j) * 128;
  const h2* rowG = wrowh + ((size_t)2 * DH + j) * 128;
  const h2* rowO = wrowh + ((size_t)3 * DH + j) * 128;

  // --- weights: 13 h8 chunks per row in named registers ---
#define DECLW(i) h8 WF_##i, WI_##i, WG_##i, WO_##i;
  CH13(DECLW)
#undef DECLW
#define LOADW(i) \
  WF_##i = *(const h8*)(const void*)(rowF + (size_t)(P16 + i) * 4); \
  WI_##i = *(const h8*)(const void*)(rowI + (size_t)(P16 + i) * 4); \
  WG_##i = *(const h8*)(const void*)(rowG + (size_t)(P16 + i) * 4); \
  WO_##i = *(const h8*)(const void*)(rowO + (size_t)(P16 + i) * 4);
  CH13(LOADW)
#undef LOADW
  // --- tail chunks 13..15 per row -> LDS ---
#pragma unroll
  for (int tt = 0; tt < 3; ++tt) {
    wtail[0 + tt][tid] = *(const h8*)(const void*)(rowF + (size_t)(P16 + 13 + tt) * 4);
    wtail[3 + tt][tid] = *(const h8*)(const void*)(rowI + (size_t)(P16 + 13 + tt) * 4);
    wtail[6 + tt][tid] = *(const h8*)(const void*)(rowG + (size_t)(P16 + 13 + tt) * 4);
    wtail[9 + tt][tid] = *(const h8*)(const void*)(rowO + (size_t)(P16 + 13 + tt) * 4);
  }

  float creg = csrc[(size_t)b * DH + j];  // replicated across the pair
  if (tid < 128) {
    h2 hv;
    hv[0] = (_Float16)hsrc[(size_t)b * DH + 2 * tid];
    hv[1] = (_Float16)hsrc[(size_t)b * DH + 2 * tid + 1];
    hbuf[0][tid] = hv;
  }
  __syncthreads();

  const size_t xstep = (size_t)NB * G4;
  // p=0 loads x-parts of rows {f,i}; p=1 loads {g,o}.
  const _Float16* xpA = Xg + (size_t)b * G4 + p * 512 + j;        // f or g
  const _Float16* xpB = xpA + 256;                                // i or o
  float xA = (float)xpA[0], xB = (float)xpB[0];
  float hlast = 0.f;

  for (int t = 0; t < Tc; ++t) {
    float xAn = 0.f, xBn = 0.f;
    if (t + 1 < Tc) {
      xAn = (float)xpA[(size_t)(t + 1) * xstep];
      xBn = (float)xpB[(size_t)(t + 1) * xstep];
    }
    const h2* hb = hbuf[t & 1] + hoff;

    // init partials with the x-part on the owning lane (counted once)
    float accF = p ? 0.f : xA;
    float accI = p ? 0.f : xB;
    float accG = p ? xA : 0.f;
    float accO = p ? xB : 0.f;

#define DOTCH(i) { \
    h8 hv = *(const h8*)(const void*)(hb + 4 * (i)); \
    accF = fdot2(sl2(WF_##i,0), sl2(hv,0), accF); \
    accF = fdot2(sl2(WF_##i,1), sl2(hv,1), accF); \
    accF = fdot2(sl2(WF_##i,2), sl2(hv,2), accF); \
    accF = fdot2(sl2(WF_##i,3), sl2(hv,3), accF); \
    accI = fdot2(sl2(WI_##i,0), sl2(hv,0), accI); \
    accI = fdot2(sl2(WI_##i,1), sl2(hv,1), accI); \
    accI = fdot2(sl2(WI_##i,2), sl2(hv,2), accI); \
    accI = fdot2(sl2(WI_##i,3), sl2(hv,3), accI); \
    accG = fdot2(sl2(WG_##i,0), sl2(hv,0), accG); \
    accG = fdot2(sl2(WG_##i,1), sl2(hv,1), accG); \
    accG = fdot2(sl2(WG_##i,2), sl2(hv,2), accG); \
    accG = fdot2(sl2(WG_##i,3), sl2(hv,3), accG); \
    accO = fdot2(sl2(WO_##i,0), sl2(hv,0), accO); \
    accO = fdot2(sl2(WO_##i,1), sl2(hv,1), accO); \
    accO = fdot2(sl2(WO_##i,2), sl2(hv,2), accO); \
    accO = fdot2(sl2(WO_##i,3), sl2(hv,3), accO); }
    CH13(DOTCH)
#undef DOTCH
#pragma unroll
    for (int tt = 0; tt < 3; ++tt) {
      h8 hv = *(const h8*)(const void*)(hb + 4 * (13 + tt));
      h8 wf = wtail[0 + tt][tid];
      h8 wi = wtail[3 + tt][tid];
      h8 wg = wtail[6 + tt][tid];
      h8 wo = wtail[9 + tt][tid];
#pragma unroll
      for (int m = 0; m < 4; ++m) {
        accF = fdot2(sl2(wf, m), sl2(hv, m), accF);
        accI = fdot2(sl2(wi, m), sl2(hv, m), accI);
        accG = fdot2(sl2(wg, m), sl2(hv, m), accG);
        accO = fdot2(sl2(wo, m), sl2(hv, m), accO);
      }
    }

    // combine K-halves across the lane pair (DPP, no LDS); both lanes get
    // identical full sums (float add is commutative).
    accF += dpp_swap1(accF);
    accI += dpp_swap1(accI);
    accG += dpp_swap1(accG);
    accO += dpp_swap1(accO);

    float f_ = sigmoid_(accF);
    float i_ = sigmoid_(accI);
    float g_ = tanh_(accG);
    float o_ = sigmoid_(accO);

    creg = f_ * creg + i_ * g_;
    float hn = o_ * tanh_(creg);
    hlast = hn;
    if (p == 0) {
      out[((size_t)(t0 + t) * NB + b) * DH + j] = hn;
    } else {
      ((_Float16*)hbuf[(t + 1) & 1])[j] = (_Float16)hn;
    }
    __syncthreads();
    xA = xAn; xB = xBn;
  }

  if (p == 0) {
    hN[(size_t)b * DH + j] = hlast;
    cN[(size_t)b * DH + j] = creg;
  }
}

// ---------------------------------------------------------------------------
extern "C" void kernel_launch(void* const* d_in, const int* in_sizes, int n_in,
                              void* d_out, int out_size, void* d_ws, size_t ws_size,
                              hipStream_t stream) {
  if (n_in < 11) return;
  const float* x  = (const float*)d_in[0];
  const float* h0 = (const float*)d_in[1];
  const float* c0 = (const float*)d_in[2];
  const float* Wf = (const float*)d_in[3];
  const float* bf = (const float*)d_in[4];
  const float* Wi = (const float*)d_in[5];
  const float* bi = (const float*)d_in[6];
  const float* Wg = (const float*)d_in[7];
  const float* bg = (const float*)d_in[8];
  const float* Wo = (const float*)d_in[9];
  const float* bo = (const float*)d_in[10];

  float* out = (float*)d_out;
  float* hN = out + (size_t)T_STEPS * NB * DH;
  float* cN = hN + (size_t)NB * DH;

  // ws layout: [Xg ring: Tc*128KB][wxhT 512KB][wrowh 512KB]
  const size_t wxhBytes = (size_t)128 * G4 * sizeof(h2);   // 512KB
  const size_t wrowBytes = (size_t)G4 * 128 * sizeof(h2);  // 512KB
  const size_t fixedBytes = wxhBytes + wrowBytes;
  size_t avail = (ws_size > fixedBytes + 256) ? ws_size - fixedBytes - 256 : 0;
  const size_t perT = (size_t)NB * G4 * 2;  // 128KB per time step
  int Tc = (int)(avail / perT);
  if (Tc > T_STEPS) Tc = T_STEPS;
  if (Tc < 1) Tc = 1;

  _Float16* Xg = (_Float16*)d_ws;
  size_t xgBytes = ((size_t)Tc * perT + 255) / 256 * 256;
  h2* wxhT = (h2*)((char*)d_ws + xgBytes);
  h2* wrowh = (h2*)((char*)d_ws + xgBytes + wxhBytes);

  kconv_w<<<dim3(512), dim3(256), 0, stream>>>(Wf, Wi, Wg, Wo, wxhT, wrowh);

  for (int t0 = 0; t0 < T_STEPS; t0 += Tc) {
    int tc = (T_STEPS - t0 < Tc) ? (T_STEPS - t0) : Tc;
    kxgemm<<<dim3(tc * 4), dim3(256), 0, stream>>>(x, wxhT, bf, bi, bg, bo, Xg, t0);
    const float* hs = (t0 == 0) ? h0 : hN;
    const float* cs = (t0 == 0) ? c0 : cN;
    klstm<<<dim3(NB), dim3(512), 0, stream>>>(wrowh, Xg, hs, cs,
                                              out, hN, cN, t0, tc);
  }
}